// Round 1
// baseline (425.386 us; speedup 1.0000x reference)
//
#include <hip/hip_runtime.h>

typedef __attribute__((ext_vector_type(8))) short short8;   // 8 bf16 (MFMA A/B frag)
typedef __attribute__((ext_vector_type(4))) float floatx4;  // MFMA C/D frag

// per-wave LDS region: 100 pixels x 20 dwords (hi[8] | lo[8] | pad[4])
// pitch 20 dwords = 80 B: 16B-aligned and (20*pix)%32 covers all bank groups.
#define PITCH 20
#define REGSZ 2000
#define LOG2E 1.44269504088896340736f
#define LN2   0.6931471805599453f

__device__ __forceinline__ float frcp(float x) { return __builtin_amdgcn_rcpf(x); }
__device__ __forceinline__ float fsoftplus(float x) {
    return fmaxf(x, 0.f) + __logf(1.f + __expf(-fabsf(x)));
}
__device__ __forceinline__ float felu(float x) { return x > 0.f ? x : __expf(x) - 1.f; }

// truncating fp32 -> (bf16 hi, bf16 lo) pair-pack: lo captures residual (err ~2^-17)
__device__ __forceinline__ void split2(float a0, float a1, unsigned& hi, unsigned& lo) {
    unsigned u0 = __float_as_uint(a0), u1 = __float_as_uint(a1);
    hi = (u0 >> 16) | (u1 & 0xffff0000u);
    float r0 = a0 - __uint_as_float(u0 & 0xffff0000u);
    float r1 = a1 - __uint_as_float(u1 & 0xffff0000u);
    lo = (__float_as_uint(r0) >> 16) | (__float_as_uint(r1) & 0xffff0000u);
}
__device__ __forceinline__ unsigned short f2bf_rne(float x) {
    unsigned u = __float_as_uint(x);
    u += 0x7fff + ((u >> 16) & 1);
    return (unsigned short)(u >> 16);
}
__device__ __forceinline__ float bf2f(unsigned short h) {
    return __uint_as_float(((unsigned)h) << 16);
}

// ---------------------------------------------------------------------------
// K1: prep (block nhist) + edge-source histogram (blocks 0..nhist-1).
// lin_w fragments are pre-scaled by log2(e) so K4's sigmoid/softplus run in
// the exp2 domain with zero per-edge scaling ops.
// ---------------------------------------------------------------------------
__global__ __launch_bounds__(256) void prep_hist_kernel(
    const float* __restrict__ edge_w, const float* __restrict__ node_w,
    const float* __restrict__ lin_w, const int* __restrict__ esrc,
    short* __restrict__ wfrag_lin, short* __restrict__ wfrag_node,
    int* __restrict__ counts, int E, int nhist)
{
    const int t = threadIdx.x;
    if ((int)blockIdx.x < nhist) {
        int i = blockIdx.x * 256 + t;
        if (i < E) atomicAdd(&counts[esrc[i]], 1);
        return;
    }
    // prep: MFMA B-fragments (bf16 hi/lo) for lin_w (scaled) and edge_w|node_w
    for (int i = t; i < 10240; i += 256) {
        int idx = i;
        int j = idx & 7; idx >>= 3;
        int lane = idx & 63; idx >>= 6;
        int s = idx % 5; idx /= 5;
        int nt = idx & 1;
        int ver = idx >> 1;
        int q = lane >> 4;
        int tap = 2 * s + (q >> 1);
        int cin = (q & 1) * 8 + j;
        {
            int cout = nt * 16 + (lane & 15);
            float v = (tap < 9) ? lin_w[cout * 144 + cin * 9 + tap] * LOG2E : 0.f;
            unsigned short hi = f2bf_rne(v);
            wfrag_lin[i] = (short)(ver ? f2bf_rne(v - bf2f(hi)) : hi);
        }
        {
            int cout = lane & 15;
            const float* src = nt ? node_w : edge_w;
            float v = (tap < 9) ? src[cout * 144 + cin * 9 + tap] : 0.f;
            unsigned short hi = f2bf_rne(v);
            wfrag_node[i] = (short)(ver ? f2bf_rne(v - bf2f(hi)) : hi);
        }
    }
}

// ---------------------------------------------------------------------------
// K2: exclusive scan of per-node edge counts (single block).
// ---------------------------------------------------------------------------
__global__ __launch_bounds__(256) void scan_kernel(
    const int* __restrict__ counts, int* __restrict__ offsets, int N)
{
    __shared__ int part[256];
    const int t = threadIdx.x;
    const int chunk = (N + 255) / 256;
    const int base = t * chunk;
    int s = 0;
    for (int i = 0; i < chunk; ++i) {
        int idx = base + i;
        if (idx < N) s += counts[idx];
    }
    part[t] = s;
    __syncthreads();
    for (int d = 1; d < 256; d <<= 1) {
        int v = (t >= d) ? part[t - d] : 0;
        __syncthreads();
        part[t] += v;
        __syncthreads();
    }
    int excl = (t == 0) ? 0 : part[t - 1];
    for (int i = 0; i < chunk; ++i) {
        int idx = base + i;
        if (idx < N) { offsets[idx] = excl; excl += counts[idx]; }
    }
    if (t == 255) offsets[N] = excl;
}

// ---------------------------------------------------------------------------
// K3: node convs via MFMA (blocks < nconv, 2 nodes/block) + edge scatter
//     (next nscat blocks) + degree-descending node order (last block).
// 128-thread blocks: no __syncthreads in the conv path (1 wave = 1 node), so
// block size is only an LDS-allocation granule. 16 KB/block -> up to 10
// blocks/CU resident (vs 3 at 32 KB / 256 threads).
// ---------------------------------------------------------------------------
__global__ __launch_bounds__(128, 4) void conv_scatter_order_kernel(
    const float* __restrict__ atom, const short* __restrict__ wfrag_node,
    float* __restrict__ zc, float* __restrict__ nc,
    const int* __restrict__ esrc, const int* __restrict__ etgt,
    const int* __restrict__ offsets, int* __restrict__ cursor,
    int* __restrict__ bucket_tgt, int* __restrict__ nlist,
    int N, int E, int nconv, int nscat)
{
    __shared__ unsigned zbuf[2 * REGSZ];     // 16 KB (conv part only)
    __shared__ int bh[64], bo[64];           // order part
    const int t = threadIdx.x;
    const int b = blockIdx.x;

    if (b >= nconv + nscat) {
        // ----- order: counting sort of nodes by degree, DESCENDING -----
        if (t < 64) bh[t] = 0;
        __syncthreads();
        for (int n = t; n < N; n += 128) {
            int deg = offsets[n + 1] - offsets[n];
            atomicAdd(&bh[min(deg, 63)], 1);
        }
        __syncthreads();
        if (t == 0) {
            int run = 0;
            for (int d = 63; d >= 0; --d) { bo[d] = run; run += bh[d]; }
        }
        __syncthreads();
        for (int n = t; n < N; n += 128) {
            int deg = offsets[n + 1] - offsets[n];
            int pos = atomicAdd(&bo[min(deg, 63)], 1);
            nlist[pos] = n;
        }
        return;
    }
    if (b >= nconv) {
        // ----- scatter: bucket edge targets by source -----
        int i = (b - nconv) * 128 + t;
        if (i < E) {
            int s = esrc[i];
            int pos = atomicAdd(&cursor[s], 1);
            bucket_tgt[offsets[s] + pos] = etgt[i];
        }
        return;
    }

    // ----- conv: 1 wave = 1 node, no barriers -----
    const int lane = t & 63;
    const int wv = t >> 6;
    const int n = b * 2 + wv;
    if (n >= N) return;
    unsigned* zb = &zbuf[wv * REGSZ];
    for (int i = lane; i < REGSZ; i += 64) zb[i] = 0u;

    const int c = lane & 15;
    const int q = lane >> 4;

    const short8* wf = (const short8*)wfrag_node;
    short8 W[2][2][5];
    #pragma unroll
    for (int v = 0; v < 2; ++v)
        #pragma unroll
        for (int nt = 0; nt < 2; ++nt)
            #pragma unroll
            for (int s = 0; s < 5; ++s)
                W[v][nt][s] = wf[(((v * 2) + nt) * 5 + s) * 64 + lane];

    int aoff[5];
    #pragma unroll
    for (int s = 0; s < 5; ++s) {
        int tap = 2 * s + (q >> 1);
        int ky = tap / 3, kx = tap - 3 * ky;
        aoff[s] = (tap < 9) ? ((((c >> 3) + ky) * 10 + (c & 7) + kx) * PITCH + (q & 1) * 4) : 0;
    }

    const size_t nb = (size_t)n * 1024;
    float a[16];
    #pragma unroll
    for (int k = 0; k < 16; ++k) a[k] = atom[nb + k * 64 + lane];
    unsigned h[8], l[8];
    #pragma unroll
    for (int d = 0; d < 8; ++d) split2(a[2 * d], a[2 * d + 1], h[d], l[d]);
    const int sbase = (((lane >> 3) + 1) * 10 + (lane & 7) + 1) * PITCH;
    *(uint4*)&zb[sbase]      = make_uint4(h[0], h[1], h[2], h[3]);
    *(uint4*)&zb[sbase + 4]  = make_uint4(h[4], h[5], h[6], h[7]);
    *(uint4*)&zb[sbase + 8]  = make_uint4(l[0], l[1], l[2], l[3]);
    *(uint4*)&zb[sbase + 12] = make_uint4(l[4], l[5], l[6], l[7]);

    #pragma unroll
    for (int mt = 0; mt < 4; ++mt) {
        floatx4 ae = {0.f, 0.f, 0.f, 0.f}, an = {0.f, 0.f, 0.f, 0.f};
        const int mb = mt * 2 * 10 * PITCH;
        #pragma unroll
        for (int s = 0; s < 5; ++s) {
            short8 Ah = *(const short8*)&zb[mb + aoff[s]];
            short8 Al = *(const short8*)&zb[mb + aoff[s] + 8];
            ae = __builtin_amdgcn_mfma_f32_16x16x32_bf16(Ah, W[0][0][s], ae, 0, 0, 0);
            an = __builtin_amdgcn_mfma_f32_16x16x32_bf16(Ah, W[0][1][s], an, 0, 0, 0);
            ae = __builtin_amdgcn_mfma_f32_16x16x32_bf16(Al, W[0][0][s], ae, 0, 0, 0);
            an = __builtin_amdgcn_mfma_f32_16x16x32_bf16(Al, W[0][1][s], an, 0, 0, 0);
            ae = __builtin_amdgcn_mfma_f32_16x16x32_bf16(Ah, W[1][0][s], ae, 0, 0, 0);
            an = __builtin_amdgcn_mfma_f32_16x16x32_bf16(Ah, W[1][1][s], an, 0, 0, 0);
        }
        *(floatx4*)&zc[nb + (size_t)c * 64 + mt * 16 + q * 4] = ae;
        *(floatx4*)&nc[nb + (size_t)c * 64 + mt * 16 + q * 4] = an;
    }
}

// ---------------------------------------------------------------------------
// K4: node-major edge processing; 1 wave = 1 node (degree-sorted via nlist).
// 128-thread blocks / 16 KB LDS: occupancy-bound fix (was 3x32KB blocks/CU).
// Epilogue runs in exp2 domain (weights pre-scaled by log2e in K1, bias
// pre-loaded into the MFMA C-init, ln2 folded back once per node).
// ---------------------------------------------------------------------------
__global__ __launch_bounds__(128, 4) void node_edge_kernel(
    const float* __restrict__ atom, const float* __restrict__ zc,
    const float* __restrict__ nc, const int* __restrict__ offsets,
    const int* __restrict__ bucket_tgt, const int* __restrict__ nlist,
    const short* __restrict__ wfrag_lin, const float* __restrict__ lin_b,
    const float* __restrict__ gamma, const float* __restrict__ beta,
    float* __restrict__ out, int N)
{
    __shared__ unsigned zbuf[2 * REGSZ];     // 16 KB
    const int t = threadIdx.x;
    const int lane = t & 63;
    const int wv = t >> 6;
    const int ni = blockIdx.x * 2 + wv;
    if (ni >= N) return;
    const int n = nlist[ni];
    const int c = lane & 15;
    const int q = lane >> 4;
    unsigned* zb = &zbuf[wv * REGSZ];
    for (int i = lane; i < REGSZ; i += 64) zb[i] = 0u;

    const short8* wf = (const short8*)wfrag_lin;
    short8 W[2][2][5];
    #pragma unroll
    for (int v = 0; v < 2; ++v)
        #pragma unroll
        for (int nt = 0; nt < 2; ++nt)
            #pragma unroll
            for (int s = 0; s < 5; ++s)
                W[v][nt][s] = wf[(((v * 2) + nt) * 5 + s) * 64 + lane];

    int aoff[5];
    #pragma unroll
    for (int s = 0; s < 5; ++s) {
        int tap = 2 * s + (q >> 1);
        int ky = tap / 3, kx = tap - 3 * ky;
        aoff[s] = (tap < 9) ? ((((c >> 3) + ky) * 10 + (c & 7) + kx) * PITCH + (q & 1) * 4) : 0;
    }

    const size_t nb = (size_t)n * 1024;
    float nv[16];
    #pragma unroll
    for (int k = 0; k < 16; ++k) nv[k] = nc[nb + k * 64 + lane];
    const int sbase = (((lane >> 3) + 1) * 10 + (lane & 7) + 1) * PITCH;

    const int off = offsets[n];
    const int deg = offsets[n + 1] - off;

    // exp2-domain biases (weights already carry the log2e factor)
    const float bf = lin_b[c] * LOG2E;
    const float bc = lin_b[c + 16] * LOG2E;
    float macc[4][4] = {{0.f}};

    float zv[16];
    int tnext = 0;
    if (deg > 0) {
        const float* zp = zc + (size_t)bucket_tgt[off] * 1024;
        #pragma unroll
        for (int k = 0; k < 16; ++k) zv[k] = zp[k * 64 + lane];
        if (deg > 1) tnext = bucket_tgt[off + 1];
    }

    for (int it = 0; it < deg; ++it) {
        float a[16];
        #pragma unroll
        for (int k = 0; k < 16; ++k) a[k] = felu(nv[k] * zv[k]);

        if (it + 1 < deg) {                  // prefetch next edge ASAP (zv consumed)
            const float* zp = zc + (size_t)tnext * 1024;
            #pragma unroll
            for (int k = 0; k < 16; ++k) zv[k] = zp[k * 64 + lane];
            if (it + 2 < deg) tnext = bucket_tgt[off + it + 2];
        }

        unsigned h[8], l[8];
        #pragma unroll
        for (int d = 0; d < 8; ++d) split2(a[2 * d], a[2 * d + 1], h[d], l[d]);
        *(uint4*)&zb[sbase]      = make_uint4(h[0], h[1], h[2], h[3]);
        *(uint4*)&zb[sbase + 4]  = make_uint4(h[4], h[5], h[6], h[7]);
        *(uint4*)&zb[sbase + 8]  = make_uint4(l[0], l[1], l[2], l[3]);
        *(uint4*)&zb[sbase + 12] = make_uint4(l[4], l[5], l[6], l[7]);

        #pragma unroll
        for (int mt = 0; mt < 4; ++mt) {
            floatx4 a0 = {bf, bf, bf, bf}, a1 = {bc, bc, bc, bc};  // bias in C-init
            const int mb = mt * 2 * 10 * PITCH;
            #pragma unroll
            for (int s = 0; s < 5; ++s) {
                short8 Ah = *(const short8*)&zb[mb + aoff[s]];
                short8 Al = *(const short8*)&zb[mb + aoff[s] + 8];
                a0 = __builtin_amdgcn_mfma_f32_16x16x32_bf16(Ah, W[0][0][s], a0, 0, 0, 0);
                a1 = __builtin_amdgcn_mfma_f32_16x16x32_bf16(Ah, W[0][1][s], a1, 0, 0, 0);
                a0 = __builtin_amdgcn_mfma_f32_16x16x32_bf16(Al, W[0][0][s], a0, 0, 0, 0);
                a1 = __builtin_amdgcn_mfma_f32_16x16x32_bf16(Al, W[0][1][s], a1, 0, 0, 0);
                a0 = __builtin_amdgcn_mfma_f32_16x16x32_bf16(Ah, W[1][0][s], a0, 0, 0, 0);
                a1 = __builtin_amdgcn_mfma_f32_16x16x32_bf16(Ah, W[1][1][s], a1, 0, 0, 0);
            }
            // sigmoid(x)*softplus(y) in exp2 domain:
            //   a0 = x*log2e, a1 = y*log2e (biases included)
            //   sig = rcp(1 + 2^-a0); sp/ln2 = max(a1,0) + log2(1 + 2^-|a1|)
            #pragma unroll
            for (int r = 0; r < 4; ++r) {
                float sg = frcp(1.f + __builtin_amdgcn_exp2f(-a0[r]));
                float e1 = __builtin_amdgcn_exp2f(-fabsf(a1[r]));
                float u = fmaxf(a1[r], 0.f) + __builtin_amdgcn_logf(1.f + e1);
                macc[mt][r] = __builtin_fmaf(sg, u, macc[mt][r]);
            }
        }
    }

    // fused BN + softplus epilogue; pixel = mt*16 + q*4 + r, cout = c
    const float scale = gamma[c] * (1.f / sqrtf(1.f + 1e-5f));
    const float bet = beta[c];
    #pragma unroll
    for (int mt = 0; mt < 4; ++mt) {
        const size_t ob = nb + (size_t)c * 64 + mt * 16 + q * 4;
        const float4 av = *(const float4*)&atom[ob];
        float av4[4] = {av.x, av.y, av.z, av.w};
        float4 ov;
        float ov4[4];
        #pragma unroll
        for (int r = 0; r < 4; ++r) {
            float aa = av4[r];
            float m = macc[mt][r] * LN2;     // fold exp2-domain factor back, once
            ov4[r] = fsoftplus(aa + (aa + m) * scale + bet);
        }
        ov.x = ov4[0]; ov.y = ov4[1]; ov.z = ov4[2]; ov.w = ov4[3];
        *(float4*)&out[ob] = ov;
    }
}

extern "C" void kernel_launch(void* const* d_in, const int* in_sizes, int n_in,
                              void* d_out, int out_size, void* d_ws, size_t ws_size,
                              hipStream_t stream) {
    const float* atom   = (const float*)d_in[0];
    const int*   esrc   = (const int*)d_in[1];
    const int*   etgt   = (const int*)d_in[2];
    const float* edge_w = (const float*)d_in[3];
    const float* node_w = (const float*)d_in[4];
    const float* lin_w  = (const float*)d_in[5];
    const float* lin_b  = (const float*)d_in[6];
    const float* gamma  = (const float*)d_in[7];
    const float* beta   = (const float*)d_in[8];
    float* out = (float*)d_out;

    const int total = in_sizes[0];      // N*16*8*8
    const int N = total / 1024;         // 8000
    const int E = in_sizes[1];          // 48000

    char* wsb = (char*)d_ws;
    float* zcb       = (float*)wsb;                                   // total fp32
    float* ncb       = (float*)(wsb + (size_t)total * 4);             // total fp32
    short* wfrag_lin = (short*)(wsb + (size_t)total * 8);             // 10240 (16B-aligned)
    short* wfrag_nod = wfrag_lin + 10240;                             // 10240
    int*   counts    = (int*)(wfrag_nod + 10240);                     // N
    int*   cursor    = counts + N;                                    // N
    int*   offsets   = cursor + N;                                    // N+1
    int*   bucket    = offsets + N + 1;                               // E
    int*   nlist     = bucket + E;                                    // N

    const int nhist = (E + 255) / 256;
    const int nconv = (N + 1) / 2;      // 128-thread blocks, 2 nodes/block
    const int nscat = (E + 127) / 128;

    hipMemsetAsync(counts, 0, (size_t)2 * N * 4, stream);             // counts+cursor
    prep_hist_kernel<<<nhist + 1, 256, 0, stream>>>(
        edge_w, node_w, lin_w, esrc, wfrag_lin, wfrag_nod, counts, E, nhist);
    scan_kernel<<<1, 256, 0, stream>>>(counts, offsets, N);
    conv_scatter_order_kernel<<<nconv + nscat + 1, 128, 0, stream>>>(
        atom, wfrag_nod, zcb, ncb, esrc, etgt, offsets, cursor, bucket, nlist,
        N, E, nconv, nscat);
    node_edge_kernel<<<nconv, 128, 0, stream>>>(
        atom, zcb, ncb, offsets, bucket, nlist, wfrag_lin, lin_b, gamma, beta, out, N);
}

// Round 2
// 271.095 us; speedup vs baseline: 1.5691x; 1.5691x over previous
//
#include <hip/hip_runtime.h>

typedef __attribute__((ext_vector_type(8))) short short8;   // 8 bf16 (MFMA A/B frag)
typedef __attribute__((ext_vector_type(4))) float floatx4;  // MFMA C/D frag

// per-wave LDS region: 100 pixels x 20 dwords (hi[8] | lo[8] | pad[4])
// pitch 20 dwords = 80 B: 16B-aligned and (20*pix)%32 covers all bank groups.
#define PITCH 20
#define REGSZ 2000
#define LOG2E 1.44269504088896340736f
#define LN2   0.6931471805599453f

__device__ __forceinline__ float frcp(float x) { return __builtin_amdgcn_rcpf(x); }
__device__ __forceinline__ float fsoftplus(float x) {
    return fmaxf(x, 0.f) + __logf(1.f + __expf(-fabsf(x)));
}
__device__ __forceinline__ float felu(float x) { return x > 0.f ? x : __expf(x) - 1.f; }

// truncating fp32 -> (bf16 hi, bf16 lo) pair-pack: lo captures residual (err ~2^-17)
__device__ __forceinline__ void split2(float a0, float a1, unsigned& hi, unsigned& lo) {
    unsigned u0 = __float_as_uint(a0), u1 = __float_as_uint(a1);
    hi = (u0 >> 16) | (u1 & 0xffff0000u);
    float r0 = a0 - __uint_as_float(u0 & 0xffff0000u);
    float r1 = a1 - __uint_as_float(u1 & 0xffff0000u);
    lo = (__float_as_uint(r0) >> 16) | (__float_as_uint(r1) & 0xffff0000u);
}
__device__ __forceinline__ unsigned short f2bf_rne(float x) {
    unsigned u = __float_as_uint(x);
    u += 0x7fff + ((u >> 16) & 1);
    return (unsigned short)(u >> 16);
}
__device__ __forceinline__ float bf2f(unsigned short h) {
    return __uint_as_float(((unsigned)h) << 16);
}

// ---------------------------------------------------------------------------
// K1: prep (block nhist) + edge-source histogram (blocks 0..nhist-1).
// lin_w fragments are pre-scaled by log2(e) so K4's sigmoid/softplus run in
// the exp2 domain with zero per-edge scaling ops.
// ---------------------------------------------------------------------------
__global__ __launch_bounds__(256) void prep_hist_kernel(
    const float* __restrict__ edge_w, const float* __restrict__ node_w,
    const float* __restrict__ lin_w, const int* __restrict__ esrc,
    short* __restrict__ wfrag_lin, short* __restrict__ wfrag_node,
    int* __restrict__ counts, int E, int nhist)
{
    const int t = threadIdx.x;
    if ((int)blockIdx.x < nhist) {
        int i = blockIdx.x * 256 + t;
        if (i < E) atomicAdd(&counts[esrc[i]], 1);
        return;
    }
    // prep: MFMA B-fragments (bf16 hi/lo) for lin_w (scaled) and edge_w|node_w
    for (int i = t; i < 10240; i += 256) {
        int idx = i;
        int j = idx & 7; idx >>= 3;
        int lane = idx & 63; idx >>= 6;
        int s = idx % 5; idx /= 5;
        int nt = idx & 1;
        int ver = idx >> 1;
        int q = lane >> 4;
        int tap = 2 * s + (q >> 1);
        int cin = (q & 1) * 8 + j;
        {
            int cout = nt * 16 + (lane & 15);
            float v = (tap < 9) ? lin_w[cout * 144 + cin * 9 + tap] * LOG2E : 0.f;
            unsigned short hi = f2bf_rne(v);
            wfrag_lin[i] = (short)(ver ? f2bf_rne(v - bf2f(hi)) : hi);
        }
        {
            int cout = lane & 15;
            const float* src = nt ? node_w : edge_w;
            float v = (tap < 9) ? src[cout * 144 + cin * 9 + tap] : 0.f;
            unsigned short hi = f2bf_rne(v);
            wfrag_node[i] = (short)(ver ? f2bf_rne(v - bf2f(hi)) : hi);
        }
    }
}

// ---------------------------------------------------------------------------
// K2: exclusive scan of per-node edge counts (single block).
// ---------------------------------------------------------------------------
__global__ __launch_bounds__(256) void scan_kernel(
    const int* __restrict__ counts, int* __restrict__ offsets, int N)
{
    __shared__ int part[256];
    const int t = threadIdx.x;
    const int chunk = (N + 255) / 256;
    const int base = t * chunk;
    int s = 0;
    for (int i = 0; i < chunk; ++i) {
        int idx = base + i;
        if (idx < N) s += counts[idx];
    }
    part[t] = s;
    __syncthreads();
    for (int d = 1; d < 256; d <<= 1) {
        int v = (t >= d) ? part[t - d] : 0;
        __syncthreads();
        part[t] += v;
        __syncthreads();
    }
    int excl = (t == 0) ? 0 : part[t - 1];
    for (int i = 0; i < chunk; ++i) {
        int idx = base + i;
        if (idx < N) { offsets[idx] = excl; excl += counts[idx]; }
    }
    if (t == 255) offsets[N] = excl;
}

// ---------------------------------------------------------------------------
// K3: node convs via MFMA (blocks < nconv, 2 nodes/block) + edge scatter
//     (next nscat blocks) + degree-descending node order (last block).
// 128-thread blocks: no __syncthreads in the conv path (1 wave = 1 node), so
// block size is only an LDS-allocation granule. 16 KB/block -> up to 10
// blocks/CU resident.
// launch_bounds(128,3): VGPR cap 168. (x,4) caps at 64 arch VGPRs on this
// VGPR+AGPR mix and SPILLS (R1: FETCH 143->686 MB, dur 127->268 us). Do not
// raise the waves/EU hint above 3 on these kernels.
// ---------------------------------------------------------------------------
__global__ __launch_bounds__(128, 3) void conv_scatter_order_kernel(
    const float* __restrict__ atom, const short* __restrict__ wfrag_node,
    float* __restrict__ zc, float* __restrict__ nc,
    const int* __restrict__ esrc, const int* __restrict__ etgt,
    const int* __restrict__ offsets, int* __restrict__ cursor,
    int* __restrict__ bucket_tgt, int* __restrict__ nlist,
    int N, int E, int nconv, int nscat)
{
    __shared__ unsigned zbuf[2 * REGSZ];     // 16 KB (conv part only)
    __shared__ int bh[64], bo[64];           // order part
    const int t = threadIdx.x;
    const int b = blockIdx.x;

    if (b >= nconv + nscat) {
        // ----- order: counting sort of nodes by degree, DESCENDING -----
        if (t < 64) bh[t] = 0;
        __syncthreads();
        for (int n = t; n < N; n += 128) {
            int deg = offsets[n + 1] - offsets[n];
            atomicAdd(&bh[min(deg, 63)], 1);
        }
        __syncthreads();
        if (t == 0) {
            int run = 0;
            for (int d = 63; d >= 0; --d) { bo[d] = run; run += bh[d]; }
        }
        __syncthreads();
        for (int n = t; n < N; n += 128) {
            int deg = offsets[n + 1] - offsets[n];
            int pos = atomicAdd(&bo[min(deg, 63)], 1);
            nlist[pos] = n;
        }
        return;
    }
    if (b >= nconv) {
        // ----- scatter: bucket edge targets by source -----
        int i = (b - nconv) * 128 + t;
        if (i < E) {
            int s = esrc[i];
            int pos = atomicAdd(&cursor[s], 1);
            bucket_tgt[offsets[s] + pos] = etgt[i];
        }
        return;
    }

    // ----- conv: 1 wave = 1 node, no barriers -----
    const int lane = t & 63;
    const int wv = t >> 6;
    const int n = b * 2 + wv;
    if (n >= N) return;
    unsigned* zb = &zbuf[wv * REGSZ];
    for (int i = lane; i < REGSZ; i += 64) zb[i] = 0u;

    const int c = lane & 15;
    const int q = lane >> 4;

    const short8* wf = (const short8*)wfrag_node;
    short8 W[2][2][5];
    #pragma unroll
    for (int v = 0; v < 2; ++v)
        #pragma unroll
        for (int nt = 0; nt < 2; ++nt)
            #pragma unroll
            for (int s = 0; s < 5; ++s)
                W[v][nt][s] = wf[(((v * 2) + nt) * 5 + s) * 64 + lane];

    int aoff[5];
    #pragma unroll
    for (int s = 0; s < 5; ++s) {
        int tap = 2 * s + (q >> 1);
        int ky = tap / 3, kx = tap - 3 * ky;
        aoff[s] = (tap < 9) ? ((((c >> 3) + ky) * 10 + (c & 7) + kx) * PITCH + (q & 1) * 4) : 0;
    }

    const size_t nb = (size_t)n * 1024;
    float a[16];
    #pragma unroll
    for (int k = 0; k < 16; ++k) a[k] = atom[nb + k * 64 + lane];
    unsigned h[8], l[8];
    #pragma unroll
    for (int d = 0; d < 8; ++d) split2(a[2 * d], a[2 * d + 1], h[d], l[d]);
    const int sbase = (((lane >> 3) + 1) * 10 + (lane & 7) + 1) * PITCH;
    *(uint4*)&zb[sbase]      = make_uint4(h[0], h[1], h[2], h[3]);
    *(uint4*)&zb[sbase + 4]  = make_uint4(h[4], h[5], h[6], h[7]);
    *(uint4*)&zb[sbase + 8]  = make_uint4(l[0], l[1], l[2], l[3]);
    *(uint4*)&zb[sbase + 12] = make_uint4(l[4], l[5], l[6], l[7]);

    #pragma unroll
    for (int mt = 0; mt < 4; ++mt) {
        floatx4 ae = {0.f, 0.f, 0.f, 0.f}, an = {0.f, 0.f, 0.f, 0.f};
        const int mb = mt * 2 * 10 * PITCH;
        #pragma unroll
        for (int s = 0; s < 5; ++s) {
            short8 Ah = *(const short8*)&zb[mb + aoff[s]];
            short8 Al = *(const short8*)&zb[mb + aoff[s] + 8];
            ae = __builtin_amdgcn_mfma_f32_16x16x32_bf16(Ah, W[0][0][s], ae, 0, 0, 0);
            an = __builtin_amdgcn_mfma_f32_16x16x32_bf16(Ah, W[0][1][s], an, 0, 0, 0);
            ae = __builtin_amdgcn_mfma_f32_16x16x32_bf16(Al, W[0][0][s], ae, 0, 0, 0);
            an = __builtin_amdgcn_mfma_f32_16x16x32_bf16(Al, W[0][1][s], an, 0, 0, 0);
            ae = __builtin_amdgcn_mfma_f32_16x16x32_bf16(Ah, W[1][0][s], ae, 0, 0, 0);
            an = __builtin_amdgcn_mfma_f32_16x16x32_bf16(Ah, W[1][1][s], an, 0, 0, 0);
        }
        *(floatx4*)&zc[nb + (size_t)c * 64 + mt * 16 + q * 4] = ae;
        *(floatx4*)&nc[nb + (size_t)c * 64 + mt * 16 + q * 4] = an;
    }
}

// ---------------------------------------------------------------------------
// K4: node-major edge processing; 1 wave = 1 node (degree-sorted via nlist).
// 128-thread blocks / 16 KB LDS (occupancy) + launch_bounds(128,3) (no spill
// -- see K3 comment; (x,4) caps VGPRs at 64 and spills to scratch).
// Epilogue runs in exp2 domain (weights pre-scaled by log2e in K1, bias
// pre-loaded into the MFMA C-init, ln2 folded back once per node).
// ---------------------------------------------------------------------------
__global__ __launch_bounds__(128, 3) void node_edge_kernel(
    const float* __restrict__ atom, const float* __restrict__ zc,
    const float* __restrict__ nc, const int* __restrict__ offsets,
    const int* __restrict__ bucket_tgt, const int* __restrict__ nlist,
    const short* __restrict__ wfrag_lin, const float* __restrict__ lin_b,
    const float* __restrict__ gamma, const float* __restrict__ beta,
    float* __restrict__ out, int N)
{
    __shared__ unsigned zbuf[2 * REGSZ];     // 16 KB
    const int t = threadIdx.x;
    const int lane = t & 63;
    const int wv = t >> 6;
    const int ni = blockIdx.x * 2 + wv;
    if (ni >= N) return;
    const int n = nlist[ni];
    const int c = lane & 15;
    const int q = lane >> 4;
    unsigned* zb = &zbuf[wv * REGSZ];
    for (int i = lane; i < REGSZ; i += 64) zb[i] = 0u;

    const short8* wf = (const short8*)wfrag_lin;
    short8 W[2][2][5];
    #pragma unroll
    for (int v = 0; v < 2; ++v)
        #pragma unroll
        for (int nt = 0; nt < 2; ++nt)
            #pragma unroll
            for (int s = 0; s < 5; ++s)
                W[v][nt][s] = wf[(((v * 2) + nt) * 5 + s) * 64 + lane];

    int aoff[5];
    #pragma unroll
    for (int s = 0; s < 5; ++s) {
        int tap = 2 * s + (q >> 1);
        int ky = tap / 3, kx = tap - 3 * ky;
        aoff[s] = (tap < 9) ? ((((c >> 3) + ky) * 10 + (c & 7) + kx) * PITCH + (q & 1) * 4) : 0;
    }

    const size_t nb = (size_t)n * 1024;
    float nv[16];
    #pragma unroll
    for (int k = 0; k < 16; ++k) nv[k] = nc[nb + k * 64 + lane];
    const int sbase = (((lane >> 3) + 1) * 10 + (lane & 7) + 1) * PITCH;

    const int off = offsets[n];
    const int deg = offsets[n + 1] - off;

    // exp2-domain biases (weights already carry the log2e factor)
    const float bf = lin_b[c] * LOG2E;
    const float bc = lin_b[c + 16] * LOG2E;
    float macc[4][4] = {{0.f}};

    float zv[16];
    int tnext = 0;
    if (deg > 0) {
        const float* zp = zc + (size_t)bucket_tgt[off] * 1024;
        #pragma unroll
        for (int k = 0; k < 16; ++k) zv[k] = zp[k * 64 + lane];
        if (deg > 1) tnext = bucket_tgt[off + 1];
    }

    for (int it = 0; it < deg; ++it) {
        float a[16];
        #pragma unroll
        for (int k = 0; k < 16; ++k) a[k] = felu(nv[k] * zv[k]);

        if (it + 1 < deg) {                  // prefetch next edge ASAP (zv consumed)
            const float* zp = zc + (size_t)tnext * 1024;
            #pragma unroll
            for (int k = 0; k < 16; ++k) zv[k] = zp[k * 64 + lane];
            if (it + 2 < deg) tnext = bucket_tgt[off + it + 2];
        }

        unsigned h[8], l[8];
        #pragma unroll
        for (int d = 0; d < 8; ++d) split2(a[2 * d], a[2 * d + 1], h[d], l[d]);
        *(uint4*)&zb[sbase]      = make_uint4(h[0], h[1], h[2], h[3]);
        *(uint4*)&zb[sbase + 4]  = make_uint4(h[4], h[5], h[6], h[7]);
        *(uint4*)&zb[sbase + 8]  = make_uint4(l[0], l[1], l[2], l[3]);
        *(uint4*)&zb[sbase + 12] = make_uint4(l[4], l[5], l[6], l[7]);

        #pragma unroll
        for (int mt = 0; mt < 4; ++mt) {
            floatx4 a0 = {bf, bf, bf, bf}, a1 = {bc, bc, bc, bc};  // bias in C-init
            const int mb = mt * 2 * 10 * PITCH;
            #pragma unroll
            for (int s = 0; s < 5; ++s) {
                short8 Ah = *(const short8*)&zb[mb + aoff[s]];
                short8 Al = *(const short8*)&zb[mb + aoff[s] + 8];
                a0 = __builtin_amdgcn_mfma_f32_16x16x32_bf16(Ah, W[0][0][s], a0, 0, 0, 0);
                a1 = __builtin_amdgcn_mfma_f32_16x16x32_bf16(Ah, W[0][1][s], a1, 0, 0, 0);
                a0 = __builtin_amdgcn_mfma_f32_16x16x32_bf16(Al, W[0][0][s], a0, 0, 0, 0);
                a1 = __builtin_amdgcn_mfma_f32_16x16x32_bf16(Al, W[0][1][s], a1, 0, 0, 0);
                a0 = __builtin_amdgcn_mfma_f32_16x16x32_bf16(Ah, W[1][0][s], a0, 0, 0, 0);
                a1 = __builtin_amdgcn_mfma_f32_16x16x32_bf16(Ah, W[1][1][s], a1, 0, 0, 0);
            }
            // sigmoid(x)*softplus(y) in exp2 domain:
            //   a0 = x*log2e, a1 = y*log2e (biases included)
            //   sig = rcp(1 + 2^-a0); sp/ln2 = max(a1,0) + log2(1 + 2^-|a1|)
            #pragma unroll
            for (int r = 0; r < 4; ++r) {
                float sg = frcp(1.f + __builtin_amdgcn_exp2f(-a0[r]));
                float e1 = __builtin_amdgcn_exp2f(-fabsf(a1[r]));
                float u = fmaxf(a1[r], 0.f) + __builtin_amdgcn_logf(1.f + e1);
                macc[mt][r] = __builtin_fmaf(sg, u, macc[mt][r]);
            }
        }
    }

    // fused BN + softplus epilogue; pixel = mt*16 + q*4 + r, cout = c
    const float scale = gamma[c] * (1.f / sqrtf(1.f + 1e-5f));
    const float bet = beta[c];
    #pragma unroll
    for (int mt = 0; mt < 4; ++mt) {
        const size_t ob = nb + (size_t)c * 64 + mt * 16 + q * 4;
        const float4 av = *(const float4*)&atom[ob];
        float av4[4] = {av.x, av.y, av.z, av.w};
        float4 ov;
        float ov4[4];
        #pragma unroll
        for (int r = 0; r < 4; ++r) {
            float aa = av4[r];
            float m = macc[mt][r] * LN2;     // fold exp2-domain factor back, once
            ov4[r] = fsoftplus(aa + (aa + m) * scale + bet);
        }
        ov.x = ov4[0]; ov.y = ov4[1]; ov.z = ov4[2]; ov.w = ov4[3];
        *(float4*)&out[ob] = ov;
    }
}

extern "C" void kernel_launch(void* const* d_in, const int* in_sizes, int n_in,
                              void* d_out, int out_size, void* d_ws, size_t ws_size,
                              hipStream_t stream) {
    const float* atom   = (const float*)d_in[0];
    const int*   esrc   = (const int*)d_in[1];
    const int*   etgt   = (const int*)d_in[2];
    const float* edge_w = (const float*)d_in[3];
    const float* node_w = (const float*)d_in[4];
    const float* lin_w  = (const float*)d_in[5];
    const float* lin_b  = (const float*)d_in[6];
    const float* gamma  = (const float*)d_in[7];
    const float* beta   = (const float*)d_in[8];
    float* out = (float*)d_out;

    const int total = in_sizes[0];      // N*16*8*8
    const int N = total / 1024;         // 8000
    const int E = in_sizes[1];          // 48000

    char* wsb = (char*)d_ws;
    float* zcb       = (float*)wsb;                                   // total fp32
    float* ncb       = (float*)(wsb + (size_t)total * 4);             // total fp32
    short* wfrag_lin = (short*)(wsb + (size_t)total * 8);             // 10240 (16B-aligned)
    short* wfrag_nod = wfrag_lin + 10240;                             // 10240
    int*   counts    = (int*)(wfrag_nod + 10240);                     // N
    int*   cursor    = counts + N;                                    // N
    int*   offsets   = cursor + N;                                    // N+1
    int*   bucket    = offsets + N + 1;                               // E
    int*   nlist     = bucket + E;                                    // N

    const int nhist = (E + 255) / 256;
    const int nconv = (N + 1) / 2;      // 128-thread blocks, 2 nodes/block
    const int nscat = (E + 127) / 128;

    hipMemsetAsync(counts, 0, (size_t)2 * N * 4, stream);             // counts+cursor
    prep_hist_kernel<<<nhist + 1, 256, 0, stream>>>(
        edge_w, node_w, lin_w, esrc, wfrag_lin, wfrag_nod, counts, E, nhist);
    scan_kernel<<<1, 256, 0, stream>>>(counts, offsets, N);
    conv_scatter_order_kernel<<<nconv + nscat + 1, 128, 0, stream>>>(
        atom, wfrag_nod, zcb, ncb, esrc, etgt, offsets, cursor, bucket, nlist,
        N, E, nconv, nscat);
    node_edge_kernel<<<nconv, 128, 0, stream>>>(
        atom, zcb, ncb, offsets, bucket, nlist, wfrag_lin, lin_b, gamma, beta, out, N);
}

// Round 3
// 243.772 us; speedup vs baseline: 1.7450x; 1.1121x over previous
//
#include <hip/hip_runtime.h>

typedef __attribute__((ext_vector_type(8))) short short8;   // 8 bf16 (MFMA A/B frag)
typedef __attribute__((ext_vector_type(4))) float floatx4;  // MFMA C/D frag

// K4 per-wave LDS region: 100 pixels x 12 dwords (hi[8] | pad[4]).
// pitch 12 dwords = 48B = 3 x 16B slots: slot stride 3 is coprime with the 8
// bank-groups, so every 8-pixel run covers all 32 banks.
#define PITCH 12
#define REGSZ 1200
// K3 keeps the full hi/lo staging (pitch 20, 2000 dwords).
#define PITCH3 20
#define REGSZ3 2000
#define LOG2E 1.44269504088896340736f
#define LN2   0.6931471805599453f

__device__ __forceinline__ float frcp(float x) { return __builtin_amdgcn_rcpf(x); }
__device__ __forceinline__ float fsoftplus(float x) {
    return fmaxf(x, 0.f) + __logf(1.f + __expf(-fabsf(x)));
}
__device__ __forceinline__ float felu(float x) { return x > 0.f ? x : __expf(x) - 1.f; }

// truncating fp32 -> (bf16 hi, bf16 lo) pair-pack: lo captures residual (err ~2^-17)
__device__ __forceinline__ void split2(float a0, float a1, unsigned& hi, unsigned& lo) {
    unsigned u0 = __float_as_uint(a0), u1 = __float_as_uint(a1);
    hi = (u0 >> 16) | (u1 & 0xffff0000u);
    float r0 = a0 - __uint_as_float(u0 & 0xffff0000u);
    float r1 = a1 - __uint_as_float(u1 & 0xffff0000u);
    lo = (__float_as_uint(r0) >> 16) | (__float_as_uint(r1) & 0xffff0000u);
}
// RNE fp32 pair -> packed bf16x2 (a0 in low half, a1 in high half)
__device__ __forceinline__ unsigned pack2_rne(float a0, float a1) {
    unsigned u0 = __float_as_uint(a0), u1 = __float_as_uint(a1);
    u0 += 0x7fff + ((u0 >> 16) & 1);
    u1 += 0x7fff + ((u1 >> 16) & 1);
    return __builtin_amdgcn_perm(u1, u0, 0x07060302);  // [u1.b3,u1.b2,u0.b3,u0.b2]
}
__device__ __forceinline__ unsigned short f2bf_rne(float x) {
    unsigned u = __float_as_uint(x);
    u += 0x7fff + ((u >> 16) & 1);
    return (unsigned short)(u >> 16);
}
__device__ __forceinline__ float bf2f(unsigned short h) {
    return __uint_as_float(((unsigned)h) << 16);
}

// ---------------------------------------------------------------------------
// K1: prep (block nhist) + edge-source histogram (blocks 0..nhist-1).
// lin_w fragments are pre-scaled by log2(e) so K4's sigmoid/softplus run in
// the exp2 domain with zero per-edge scaling ops.
// ---------------------------------------------------------------------------
__global__ __launch_bounds__(256) void prep_hist_kernel(
    const float* __restrict__ edge_w, const float* __restrict__ node_w,
    const float* __restrict__ lin_w, const int* __restrict__ esrc,
    short* __restrict__ wfrag_lin, short* __restrict__ wfrag_node,
    int* __restrict__ counts, int E, int nhist)
{
    const int t = threadIdx.x;
    if ((int)blockIdx.x < nhist) {
        int i = blockIdx.x * 256 + t;
        if (i < E) atomicAdd(&counts[esrc[i]], 1);
        return;
    }
    // prep: MFMA B-fragments (bf16 hi/lo) for lin_w (scaled) and edge_w|node_w
    for (int i = t; i < 10240; i += 256) {
        int idx = i;
        int j = idx & 7; idx >>= 3;
        int lane = idx & 63; idx >>= 6;
        int s = idx % 5; idx /= 5;
        int nt = idx & 1;
        int ver = idx >> 1;
        int q = lane >> 4;
        int tap = 2 * s + (q >> 1);
        int cin = (q & 1) * 8 + j;
        {
            int cout = nt * 16 + (lane & 15);
            float v = (tap < 9) ? lin_w[cout * 144 + cin * 9 + tap] * LOG2E : 0.f;
            unsigned short hi = f2bf_rne(v);
            wfrag_lin[i] = (short)(ver ? f2bf_rne(v - bf2f(hi)) : hi);
        }
        {
            int cout = lane & 15;
            const float* src = nt ? node_w : edge_w;
            float v = (tap < 9) ? src[cout * 144 + cin * 9 + tap] : 0.f;
            unsigned short hi = f2bf_rne(v);
            wfrag_node[i] = (short)(ver ? f2bf_rne(v - bf2f(hi)) : hi);
        }
    }
}

// ---------------------------------------------------------------------------
// K2: exclusive scan of per-node edge counts (single block).
// ---------------------------------------------------------------------------
__global__ __launch_bounds__(256) void scan_kernel(
    const int* __restrict__ counts, int* __restrict__ offsets, int N)
{
    __shared__ int part[256];
    const int t = threadIdx.x;
    const int chunk = (N + 255) / 256;
    const int base = t * chunk;
    int s = 0;
    for (int i = 0; i < chunk; ++i) {
        int idx = base + i;
        if (idx < N) s += counts[idx];
    }
    part[t] = s;
    __syncthreads();
    for (int d = 1; d < 256; d <<= 1) {
        int v = (t >= d) ? part[t - d] : 0;
        __syncthreads();
        part[t] += v;
        __syncthreads();
    }
    int excl = (t == 0) ? 0 : part[t - 1];
    for (int i = 0; i < chunk; ++i) {
        int idx = base + i;
        if (idx < N) { offsets[idx] = excl; excl += counts[idx]; }
    }
    if (t == 255) offsets[N] = excl;
}

// ---------------------------------------------------------------------------
// K3: node convs via MFMA (blocks < nconv, 2 nodes/block) + edge scatter
//     (next nscat blocks) + degree-descending node order (last block).
// FULL hi/lo precision on both operands (outputs zc/nc feed K4's products).
// launch_bounds(128,3): VGPR cap 168. (x,4) caps at 64 arch VGPRs on this
// VGPR+AGPR mix and SPILLS (R1: FETCH 143->686 MB, dur 127->268 us). Do not
// raise the waves/EU hint above 3 on these kernels.
// ---------------------------------------------------------------------------
__global__ __launch_bounds__(128, 3) void conv_scatter_order_kernel(
    const float* __restrict__ atom, const short* __restrict__ wfrag_node,
    float* __restrict__ zc, float* __restrict__ nc,
    const int* __restrict__ esrc, const int* __restrict__ etgt,
    const int* __restrict__ offsets, int* __restrict__ cursor,
    int* __restrict__ bucket_tgt, int* __restrict__ nlist,
    int N, int E, int nconv, int nscat)
{
    __shared__ unsigned zbuf[2 * REGSZ3];    // 16 KB (conv part only)
    __shared__ int bh[64], bo[64];           // order part
    const int t = threadIdx.x;
    const int b = blockIdx.x;

    if (b >= nconv + nscat) {
        // ----- order: counting sort of nodes by degree, DESCENDING -----
        if (t < 64) bh[t] = 0;
        __syncthreads();
        for (int n = t; n < N; n += 128) {
            int deg = offsets[n + 1] - offsets[n];
            atomicAdd(&bh[min(deg, 63)], 1);
        }
        __syncthreads();
        if (t == 0) {
            int run = 0;
            for (int d = 63; d >= 0; --d) { bo[d] = run; run += bh[d]; }
        }
        __syncthreads();
        for (int n = t; n < N; n += 128) {
            int deg = offsets[n + 1] - offsets[n];
            int pos = atomicAdd(&bo[min(deg, 63)], 1);
            nlist[pos] = n;
        }
        return;
    }
    if (b >= nconv) {
        // ----- scatter: bucket edge targets by source -----
        int i = (b - nconv) * 128 + t;
        if (i < E) {
            int s = esrc[i];
            int pos = atomicAdd(&cursor[s], 1);
            bucket_tgt[offsets[s] + pos] = etgt[i];
        }
        return;
    }

    // ----- conv: 1 wave = 1 node, no barriers -----
    const int lane = t & 63;
    const int wv = t >> 6;
    const int n = b * 2 + wv;
    if (n >= N) return;
    unsigned* zb = &zbuf[wv * REGSZ3];
    for (int i = lane; i < REGSZ3; i += 64) zb[i] = 0u;

    const int c = lane & 15;
    const int q = lane >> 4;

    const short8* wf = (const short8*)wfrag_node;
    short8 W[2][2][5];
    #pragma unroll
    for (int v = 0; v < 2; ++v)
        #pragma unroll
        for (int nt = 0; nt < 2; ++nt)
            #pragma unroll
            for (int s = 0; s < 5; ++s)
                W[v][nt][s] = wf[(((v * 2) + nt) * 5 + s) * 64 + lane];

    int aoff[5];
    #pragma unroll
    for (int s = 0; s < 5; ++s) {
        int tap = 2 * s + (q >> 1);
        int ky = tap / 3, kx = tap - 3 * ky;
        aoff[s] = (tap < 9) ? ((((c >> 3) + ky) * 10 + (c & 7) + kx) * PITCH3 + (q & 1) * 4) : 0;
    }

    const size_t nb = (size_t)n * 1024;
    float a[16];
    #pragma unroll
    for (int k = 0; k < 16; ++k) a[k] = atom[nb + k * 64 + lane];
    unsigned h[8], l[8];
    #pragma unroll
    for (int d = 0; d < 8; ++d) split2(a[2 * d], a[2 * d + 1], h[d], l[d]);
    const int sbase = (((lane >> 3) + 1) * 10 + (lane & 7) + 1) * PITCH3;
    *(uint4*)&zb[sbase]      = make_uint4(h[0], h[1], h[2], h[3]);
    *(uint4*)&zb[sbase + 4]  = make_uint4(h[4], h[5], h[6], h[7]);
    *(uint4*)&zb[sbase + 8]  = make_uint4(l[0], l[1], l[2], l[3]);
    *(uint4*)&zb[sbase + 12] = make_uint4(l[4], l[5], l[6], l[7]);

    #pragma unroll
    for (int mt = 0; mt < 4; ++mt) {
        floatx4 ae = {0.f, 0.f, 0.f, 0.f}, an = {0.f, 0.f, 0.f, 0.f};
        const int mb = mt * 2 * 10 * PITCH3;
        #pragma unroll
        for (int s = 0; s < 5; ++s) {
            short8 Ah = *(const short8*)&zb[mb + aoff[s]];
            short8 Al = *(const short8*)&zb[mb + aoff[s] + 8];
            ae = __builtin_amdgcn_mfma_f32_16x16x32_bf16(Ah, W[0][0][s], ae, 0, 0, 0);
            an = __builtin_amdgcn_mfma_f32_16x16x32_bf16(Ah, W[0][1][s], an, 0, 0, 0);
            ae = __builtin_amdgcn_mfma_f32_16x16x32_bf16(Al, W[0][0][s], ae, 0, 0, 0);
            an = __builtin_amdgcn_mfma_f32_16x16x32_bf16(Al, W[0][1][s], an, 0, 0, 0);
            ae = __builtin_amdgcn_mfma_f32_16x16x32_bf16(Ah, W[1][0][s], ae, 0, 0, 0);
            an = __builtin_amdgcn_mfma_f32_16x16x32_bf16(Ah, W[1][1][s], an, 0, 0, 0);
        }
        *(floatx4*)&zc[nb + (size_t)c * 64 + mt * 16 + q * 4] = ae;
        *(floatx4*)&nc[nb + (size_t)c * 64 + mt * 16 + q * 4] = an;
    }
}

// ---------------------------------------------------------------------------
// K4: node-major edge processing; 1 wave = 1 node (degree-sorted via nlist).
// R3 change: A operand staged as SINGLE RNE bf16 (was hi/lo pair); weights
// keep hi+lo, so the product is A_bf16 x W_f32. A-rounding error (~2^-9 rel)
// is decorrelated across edges -> sums like sqrt(deg). Per edge: LDS ops
// 44 -> 22, MFMA 120 -> 80, split-pack VALU halved, staging 8 -> 4.8 KB/wave.
// launch_bounds(128,3): no spill (see K3 comment).
// ---------------------------------------------------------------------------
__global__ __launch_bounds__(128, 3) void node_edge_kernel(
    const float* __restrict__ atom, const float* __restrict__ zc,
    const float* __restrict__ nc, const int* __restrict__ offsets,
    const int* __restrict__ bucket_tgt, const int* __restrict__ nlist,
    const short* __restrict__ wfrag_lin, const float* __restrict__ lin_b,
    const float* __restrict__ gamma, const float* __restrict__ beta,
    float* __restrict__ out, int N)
{
    __shared__ unsigned zbuf[2 * REGSZ];     // 9.6 KB
    const int t = threadIdx.x;
    const int lane = t & 63;
    const int wv = t >> 6;
    const int ni = blockIdx.x * 2 + wv;
    if (ni >= N) return;
    const int n = nlist[ni];
    const int c = lane & 15;
    const int q = lane >> 4;
    unsigned* zb = &zbuf[wv * REGSZ];
    for (int i = lane; i < REGSZ; i += 64) zb[i] = 0u;

    const short8* wf = (const short8*)wfrag_lin;
    short8 W[2][2][5];
    #pragma unroll
    for (int v = 0; v < 2; ++v)
        #pragma unroll
        for (int nt = 0; nt < 2; ++nt)
            #pragma unroll
            for (int s = 0; s < 5; ++s)
                W[v][nt][s] = wf[(((v * 2) + nt) * 5 + s) * 64 + lane];

    int aoff[5];
    #pragma unroll
    for (int s = 0; s < 5; ++s) {
        int tap = 2 * s + (q >> 1);
        int ky = tap / 3, kx = tap - 3 * ky;
        aoff[s] = (tap < 9) ? ((((c >> 3) + ky) * 10 + (c & 7) + kx) * PITCH + (q & 1) * 4) : 0;
    }

    const size_t nb = (size_t)n * 1024;
    float nv[16];
    #pragma unroll
    for (int k = 0; k < 16; ++k) nv[k] = nc[nb + k * 64 + lane];
    const int sbase = (((lane >> 3) + 1) * 10 + (lane & 7) + 1) * PITCH;

    const int off = offsets[n];
    const int deg = offsets[n + 1] - off;

    // exp2-domain biases (weights already carry the log2e factor)
    const float bf = lin_b[c] * LOG2E;
    const float bc = lin_b[c + 16] * LOG2E;
    float macc[4][4] = {{0.f}};

    float zv[16];
    int tnext = 0;
    if (deg > 0) {
        const float* zp = zc + (size_t)bucket_tgt[off] * 1024;
        #pragma unroll
        for (int k = 0; k < 16; ++k) zv[k] = zp[k * 64 + lane];
        if (deg > 1) tnext = bucket_tgt[off + 1];
    }

    for (int it = 0; it < deg; ++it) {
        float a[16];
        #pragma unroll
        for (int k = 0; k < 16; ++k) a[k] = felu(nv[k] * zv[k]);

        if (it + 1 < deg) {                  // prefetch next edge ASAP (zv consumed)
            const float* zp = zc + (size_t)tnext * 1024;
            #pragma unroll
            for (int k = 0; k < 16; ++k) zv[k] = zp[k * 64 + lane];
            if (it + 2 < deg) tnext = bucket_tgt[off + it + 2];
        }

        unsigned h[8];
        #pragma unroll
        for (int d = 0; d < 8; ++d) h[d] = pack2_rne(a[2 * d], a[2 * d + 1]);
        *(uint4*)&zb[sbase]     = make_uint4(h[0], h[1], h[2], h[3]);
        *(uint4*)&zb[sbase + 4] = make_uint4(h[4], h[5], h[6], h[7]);

        #pragma unroll
        for (int mt = 0; mt < 4; ++mt) {
            floatx4 a0 = {bf, bf, bf, bf}, a1 = {bc, bc, bc, bc};  // bias in C-init
            const int mb = mt * 2 * 10 * PITCH;
            #pragma unroll
            for (int s = 0; s < 5; ++s) {
                short8 Ah = *(const short8*)&zb[mb + aoff[s]];
                a0 = __builtin_amdgcn_mfma_f32_16x16x32_bf16(Ah, W[0][0][s], a0, 0, 0, 0);
                a1 = __builtin_amdgcn_mfma_f32_16x16x32_bf16(Ah, W[0][1][s], a1, 0, 0, 0);
                a0 = __builtin_amdgcn_mfma_f32_16x16x32_bf16(Ah, W[1][0][s], a0, 0, 0, 0);
                a1 = __builtin_amdgcn_mfma_f32_16x16x32_bf16(Ah, W[1][1][s], a1, 0, 0, 0);
            }
            // sigmoid(x)*softplus(y) in exp2 domain:
            //   a0 = x*log2e, a1 = y*log2e (biases included)
            //   sig = rcp(1 + 2^-a0); sp/ln2 = max(a1,0) + log2(1 + 2^-|a1|)
            #pragma unroll
            for (int r = 0; r < 4; ++r) {
                float sg = frcp(1.f + __builtin_amdgcn_exp2f(-a0[r]));
                float e1 = __builtin_amdgcn_exp2f(-fabsf(a1[r]));
                float u = fmaxf(a1[r], 0.f) + __builtin_amdgcn_logf(1.f + e1);
                macc[mt][r] = __builtin_fmaf(sg, u, macc[mt][r]);
            }
        }
    }

    // fused BN + softplus epilogue; pixel = mt*16 + q*4 + r, cout = c
    const float scale = gamma[c] * (1.f / sqrtf(1.f + 1e-5f));
    const float bet = beta[c];
    #pragma unroll
    for (int mt = 0; mt < 4; ++mt) {
        const size_t ob = nb + (size_t)c * 64 + mt * 16 + q * 4;
        const float4 av = *(const float4*)&atom[ob];
        float av4[4] = {av.x, av.y, av.z, av.w};
        float4 ov;
        float ov4[4];
        #pragma unroll
        for (int r = 0; r < 4; ++r) {
            float aa = av4[r];
            float m = macc[mt][r] * LN2;     // fold exp2-domain factor back, once
            ov4[r] = fsoftplus(aa + (aa + m) * scale + bet);
        }
        ov.x = ov4[0]; ov.y = ov4[1]; ov.z = ov4[2]; ov.w = ov4[3];
        *(float4*)&out[ob] = ov;
    }
}

extern "C" void kernel_launch(void* const* d_in, const int* in_sizes, int n_in,
                              void* d_out, int out_size, void* d_ws, size_t ws_size,
                              hipStream_t stream) {
    const float* atom   = (const float*)d_in[0];
    const int*   esrc   = (const int*)d_in[1];
    const int*   etgt   = (const int*)d_in[2];
    const float* edge_w = (const float*)d_in[3];
    const float* node_w = (const float*)d_in[4];
    const float* lin_w  = (const float*)d_in[5];
    const float* lin_b  = (const float*)d_in[6];
    const float* gamma  = (const float*)d_in[7];
    const float* beta   = (const float*)d_in[8];
    float* out = (float*)d_out;

    const int total = in_sizes[0];      // N*16*8*8
    const int N = total / 1024;         // 8000
    const int E = in_sizes[1];          // 48000

    char* wsb = (char*)d_ws;
    float* zcb       = (float*)wsb;                                   // total fp32
    float* ncb       = (float*)(wsb + (size_t)total * 4);             // total fp32
    short* wfrag_lin = (short*)(wsb + (size_t)total * 8);             // 10240 (16B-aligned)
    short* wfrag_nod = wfrag_lin + 10240;                             // 10240
    int*   counts    = (int*)(wfrag_nod + 10240);                     // N
    int*   cursor    = counts + N;                                    // N
    int*   offsets   = cursor + N;                                    // N+1
    int*   bucket    = offsets + N + 1;                               // E
    int*   nlist     = bucket + E;                                    // N

    const int nhist = (E + 255) / 256;
    const int nconv = (N + 1) / 2;      // 128-thread blocks, 2 nodes/block
    const int nscat = (E + 127) / 128;

    hipMemsetAsync(counts, 0, (size_t)2 * N * 4, stream);             // counts+cursor
    prep_hist_kernel<<<nhist + 1, 256, 0, stream>>>(
        edge_w, node_w, lin_w, esrc, wfrag_lin, wfrag_nod, counts, E, nhist);
    scan_kernel<<<1, 256, 0, stream>>>(counts, offsets, N);
    conv_scatter_order_kernel<<<nconv + nscat + 1, 128, 0, stream>>>(
        atom, wfrag_nod, zcb, ncb, esrc, etgt, offsets, cursor, bucket, nlist,
        N, E, nconv, nscat);
    node_edge_kernel<<<nconv, 128, 0, stream>>>(
        atom, zcb, ncb, offsets, bucket, nlist, wfrag_lin, lin_b, gamma, beta, out, N);
}

// Round 4
// 225.490 us; speedup vs baseline: 1.8865x; 1.0811x over previous
//
#include <hip/hip_runtime.h>

typedef __attribute__((ext_vector_type(8))) short short8;   // 8 bf16 (MFMA A/B frag)
typedef __attribute__((ext_vector_type(4))) float floatx4;  // MFMA C/D frag

// Shared per-wave LDS staging (K3 & K4): 100 pixels x 12 dwords (bf16x2[8] | pad[4]).
// pitch 12 dwords = 48B = 3 x 16B slots: slot stride 3 is coprime with the 8
// bank-groups, so every 8-pixel run covers all 32 banks.
#define PITCH 12
#define REGSZ 1200
#define LOG2E 1.44269504088896340736f
#define LN2   0.6931471805599453f

__device__ __forceinline__ float frcp(float x) { return __builtin_amdgcn_rcpf(x); }
__device__ __forceinline__ float fsoftplus(float x) {
    return fmaxf(x, 0.f) + __logf(1.f + __expf(-fabsf(x)));
}
__device__ __forceinline__ float felu(float x) { return x > 0.f ? x : __expf(x) - 1.f; }

// RNE fp32 pair -> packed bf16x2 (a0 in low half, a1 in high half)
__device__ __forceinline__ unsigned pack2_rne(float a0, float a1) {
    unsigned u0 = __float_as_uint(a0), u1 = __float_as_uint(a1);
    u0 += 0x7fff + ((u0 >> 16) & 1);
    u1 += 0x7fff + ((u1 >> 16) & 1);
    return __builtin_amdgcn_perm(u1, u0, 0x07060302);  // [u1.b3,u1.b2,u0.b3,u0.b2]
}
__device__ __forceinline__ unsigned short f2bf_rne(float x) {
    unsigned u = __float_as_uint(x);
    u += 0x7fff + ((u >> 16) & 1);
    return (unsigned short)(u >> 16);
}
__device__ __forceinline__ float bf2f(unsigned short h) {
    return __uint_as_float(((unsigned)h) << 16);
}

// ---------------------------------------------------------------------------
// K1: prep (block nhist) + edge-source histogram (blocks 0..nhist-1).
// lin_w fragments are pre-scaled by log2(e) so K4's sigmoid/softplus run in
// the exp2 domain with zero per-edge scaling ops.
// ---------------------------------------------------------------------------
__global__ __launch_bounds__(256) void prep_hist_kernel(
    const float* __restrict__ edge_w, const float* __restrict__ node_w,
    const float* __restrict__ lin_w, const int* __restrict__ esrc,
    short* __restrict__ wfrag_lin, short* __restrict__ wfrag_node,
    int* __restrict__ counts, int E, int nhist)
{
    const int t = threadIdx.x;
    if ((int)blockIdx.x < nhist) {
        int i = blockIdx.x * 256 + t;
        if (i < E) atomicAdd(&counts[esrc[i]], 1);
        return;
    }
    // prep: MFMA B-fragments (bf16 hi/lo) for lin_w (scaled) and edge_w|node_w
    for (int i = t; i < 10240; i += 256) {
        int idx = i;
        int j = idx & 7; idx >>= 3;
        int lane = idx & 63; idx >>= 6;
        int s = idx % 5; idx /= 5;
        int nt = idx & 1;
        int ver = idx >> 1;
        int q = lane >> 4;
        int tap = 2 * s + (q >> 1);
        int cin = (q & 1) * 8 + j;
        {
            int cout = nt * 16 + (lane & 15);
            float v = (tap < 9) ? lin_w[cout * 144 + cin * 9 + tap] * LOG2E : 0.f;
            unsigned short hi = f2bf_rne(v);
            wfrag_lin[i] = (short)(ver ? f2bf_rne(v - bf2f(hi)) : hi);
        }
        {
            int cout = lane & 15;
            const float* src = nt ? node_w : edge_w;
            float v = (tap < 9) ? src[cout * 144 + cin * 9 + tap] : 0.f;
            unsigned short hi = f2bf_rne(v);
            wfrag_node[i] = (short)(ver ? f2bf_rne(v - bf2f(hi)) : hi);
        }
    }
}

// ---------------------------------------------------------------------------
// K2: exclusive scan of per-node edge counts (single block).
// ---------------------------------------------------------------------------
__global__ __launch_bounds__(256) void scan_kernel(
    const int* __restrict__ counts, int* __restrict__ offsets, int N)
{
    __shared__ int part[256];
    const int t = threadIdx.x;
    const int chunk = (N + 255) / 256;
    const int base = t * chunk;
    int s = 0;
    for (int i = 0; i < chunk; ++i) {
        int idx = base + i;
        if (idx < N) s += counts[idx];
    }
    part[t] = s;
    __syncthreads();
    for (int d = 1; d < 256; d <<= 1) {
        int v = (t >= d) ? part[t - d] : 0;
        __syncthreads();
        part[t] += v;
        __syncthreads();
    }
    int excl = (t == 0) ? 0 : part[t - 1];
    for (int i = 0; i < chunk; ++i) {
        int idx = base + i;
        if (idx < N) { offsets[idx] = excl; excl += counts[idx]; }
    }
    if (t == 255) offsets[N] = excl;
}

// ---------------------------------------------------------------------------
// K3: node convs via MFMA (blocks < nconv, 4 nodes/block) + edge scatter
//     (next nscat blocks) + degree-descending node order (last block).
// R4: back to 256-thread / 4-node blocks (R0 vs R2 rest-delta showed 128-thr
// cost ~26 us: worse atom locality, 2x grid) and A staged as SINGLE RNE bf16
// (R3-proven on K4: absmax bit-identical). W keeps hi+lo -> A_bf16 x W_f32.
// Per node: MFMA 120 -> 80, LDS ops 44 -> 22, staging 19.2 KB/block.
// launch_bounds(256,3): VGPR cap 168. (x,4) caps at 64 arch VGPRs and SPILLS
// (R1: FETCH 143->686 MB, dur 127->268 us). Keep waves/EU hint at 3.
// ---------------------------------------------------------------------------
__global__ __launch_bounds__(256, 3) void conv_scatter_order_kernel(
    const float* __restrict__ atom, const short* __restrict__ wfrag_node,
    float* __restrict__ zc, float* __restrict__ nc,
    const int* __restrict__ esrc, const int* __restrict__ etgt,
    const int* __restrict__ offsets, int* __restrict__ cursor,
    int* __restrict__ bucket_tgt, int* __restrict__ nlist,
    int N, int E, int nconv, int nscat)
{
    __shared__ unsigned zbuf[4 * REGSZ];     // 19.2 KB (conv part only)
    __shared__ int bh[64], bo[64];           // order part
    const int t = threadIdx.x;
    const int b = blockIdx.x;

    if (b >= nconv + nscat) {
        // ----- order: counting sort of nodes by degree, DESCENDING -----
        if (t < 64) bh[t] = 0;
        __syncthreads();
        for (int n = t; n < N; n += 256) {
            int deg = offsets[n + 1] - offsets[n];
            atomicAdd(&bh[min(deg, 63)], 1);
        }
        __syncthreads();
        if (t == 0) {
            int run = 0;
            for (int d = 63; d >= 0; --d) { bo[d] = run; run += bh[d]; }
        }
        __syncthreads();
        for (int n = t; n < N; n += 256) {
            int deg = offsets[n + 1] - offsets[n];
            int pos = atomicAdd(&bo[min(deg, 63)], 1);
            nlist[pos] = n;
        }
        return;
    }
    if (b >= nconv) {
        // ----- scatter: bucket edge targets by source -----
        int i = (b - nconv) * 256 + t;
        if (i < E) {
            int s = esrc[i];
            int pos = atomicAdd(&cursor[s], 1);
            bucket_tgt[offsets[s] + pos] = etgt[i];
        }
        return;
    }

    // ----- conv: 1 wave = 1 node, no barriers -----
    const int lane = t & 63;
    const int wv = t >> 6;
    const int n = b * 4 + wv;
    if (n >= N) return;
    unsigned* zb = &zbuf[wv * REGSZ];
    for (int i = lane; i < REGSZ; i += 64) zb[i] = 0u;

    const int c = lane & 15;
    const int q = lane >> 4;

    const short8* wf = (const short8*)wfrag_node;
    short8 W[2][2][5];
    #pragma unroll
    for (int v = 0; v < 2; ++v)
        #pragma unroll
        for (int nt = 0; nt < 2; ++nt)
            #pragma unroll
            for (int s = 0; s < 5; ++s)
                W[v][nt][s] = wf[(((v * 2) + nt) * 5 + s) * 64 + lane];

    int aoff[5];
    #pragma unroll
    for (int s = 0; s < 5; ++s) {
        int tap = 2 * s + (q >> 1);
        int ky = tap / 3, kx = tap - 3 * ky;
        aoff[s] = (tap < 9) ? ((((c >> 3) + ky) * 10 + (c & 7) + kx) * PITCH + (q & 1) * 4) : 0;
    }

    const size_t nb = (size_t)n * 1024;
    float a[16];
    #pragma unroll
    for (int k = 0; k < 16; ++k) a[k] = atom[nb + k * 64 + lane];
    unsigned h[8];
    #pragma unroll
    for (int d = 0; d < 8; ++d) h[d] = pack2_rne(a[2 * d], a[2 * d + 1]);
    const int sbase = (((lane >> 3) + 1) * 10 + (lane & 7) + 1) * PITCH;
    *(uint4*)&zb[sbase]     = make_uint4(h[0], h[1], h[2], h[3]);
    *(uint4*)&zb[sbase + 4] = make_uint4(h[4], h[5], h[6], h[7]);

    #pragma unroll
    for (int mt = 0; mt < 4; ++mt) {
        floatx4 ae = {0.f, 0.f, 0.f, 0.f}, an = {0.f, 0.f, 0.f, 0.f};
        const int mb = mt * 2 * 10 * PITCH;
        #pragma unroll
        for (int s = 0; s < 5; ++s) {
            short8 Ah = *(const short8*)&zb[mb + aoff[s]];
            ae = __builtin_amdgcn_mfma_f32_16x16x32_bf16(Ah, W[0][0][s], ae, 0, 0, 0);
            an = __builtin_amdgcn_mfma_f32_16x16x32_bf16(Ah, W[0][1][s], an, 0, 0, 0);
            ae = __builtin_amdgcn_mfma_f32_16x16x32_bf16(Ah, W[1][0][s], ae, 0, 0, 0);
            an = __builtin_amdgcn_mfma_f32_16x16x32_bf16(Ah, W[1][1][s], an, 0, 0, 0);
        }
        *(floatx4*)&zc[nb + (size_t)c * 64 + mt * 16 + q * 4] = ae;
        *(floatx4*)&nc[nb + (size_t)c * 64 + mt * 16 + q * 4] = an;
    }
}

// ---------------------------------------------------------------------------
// K4: node-major edge processing; 1 wave = 1 node (degree-sorted via nlist).
// A operand staged as SINGLE RNE bf16; weights hi+lo (A_bf16 x W_f32); A-
// rounding error (~2^-9 rel) decorrelated across edges -> sums like sqrt(deg).
// Per edge: 22 LDS ops, 80 MFMA. Epilogue in exp2 domain (weights pre-scaled
// by log2e in K1, bias in the MFMA C-init, ln2 folded back once per node).
// launch_bounds(128,3): no spill (see K3 comment; (x,4) caps at 64 and spills).
// ---------------------------------------------------------------------------
__global__ __launch_bounds__(128, 3) void node_edge_kernel(
    const float* __restrict__ atom, const float* __restrict__ zc,
    const float* __restrict__ nc, const int* __restrict__ offsets,
    const int* __restrict__ bucket_tgt, const int* __restrict__ nlist,
    const short* __restrict__ wfrag_lin, const float* __restrict__ lin_b,
    const float* __restrict__ gamma, const float* __restrict__ beta,
    float* __restrict__ out, int N)
{
    __shared__ unsigned zbuf[2 * REGSZ];     // 9.6 KB
    const int t = threadIdx.x;
    const int lane = t & 63;
    const int wv = t >> 6;
    const int ni = blockIdx.x * 2 + wv;
    if (ni >= N) return;
    const int n = nlist[ni];
    const int c = lane & 15;
    const int q = lane >> 4;
    unsigned* zb = &zbuf[wv * REGSZ];
    for (int i = lane; i < REGSZ; i += 64) zb[i] = 0u;

    const short8* wf = (const short8*)wfrag_lin;
    short8 W[2][2][5];
    #pragma unroll
    for (int v = 0; v < 2; ++v)
        #pragma unroll
        for (int nt = 0; nt < 2; ++nt)
            #pragma unroll
            for (int s = 0; s < 5; ++s)
                W[v][nt][s] = wf[(((v * 2) + nt) * 5 + s) * 64 + lane];

    int aoff[5];
    #pragma unroll
    for (int s = 0; s < 5; ++s) {
        int tap = 2 * s + (q >> 1);
        int ky = tap / 3, kx = tap - 3 * ky;
        aoff[s] = (tap < 9) ? ((((c >> 3) + ky) * 10 + (c & 7) + kx) * PITCH + (q & 1) * 4) : 0;
    }

    const size_t nb = (size_t)n * 1024;
    float nv[16];
    #pragma unroll
    for (int k = 0; k < 16; ++k) nv[k] = nc[nb + k * 64 + lane];
    const int sbase = (((lane >> 3) + 1) * 10 + (lane & 7) + 1) * PITCH;

    const int off = offsets[n];
    const int deg = offsets[n + 1] - off;

    // exp2-domain biases (weights already carry the log2e factor)
    const float bf = lin_b[c] * LOG2E;
    const float bc = lin_b[c + 16] * LOG2E;
    float macc[4][4] = {{0.f}};

    float zv[16];
    int tnext = 0;
    if (deg > 0) {
        const float* zp = zc + (size_t)bucket_tgt[off] * 1024;
        #pragma unroll
        for (int k = 0; k < 16; ++k) zv[k] = zp[k * 64 + lane];
        if (deg > 1) tnext = bucket_tgt[off + 1];
    }

    for (int it = 0; it < deg; ++it) {
        float a[16];
        #pragma unroll
        for (int k = 0; k < 16; ++k) a[k] = felu(nv[k] * zv[k]);

        if (it + 1 < deg) {                  // prefetch next edge ASAP (zv consumed)
            const float* zp = zc + (size_t)tnext * 1024;
            #pragma unroll
            for (int k = 0; k < 16; ++k) zv[k] = zp[k * 64 + lane];
            if (it + 2 < deg) tnext = bucket_tgt[off + it + 2];
        }

        unsigned h[8];
        #pragma unroll
        for (int d = 0; d < 8; ++d) h[d] = pack2_rne(a[2 * d], a[2 * d + 1]);
        *(uint4*)&zb[sbase]     = make_uint4(h[0], h[1], h[2], h[3]);
        *(uint4*)&zb[sbase + 4] = make_uint4(h[4], h[5], h[6], h[7]);

        #pragma unroll
        for (int mt = 0; mt < 4; ++mt) {
            floatx4 a0 = {bf, bf, bf, bf}, a1 = {bc, bc, bc, bc};  // bias in C-init
            const int mb = mt * 2 * 10 * PITCH;
            #pragma unroll
            for (int s = 0; s < 5; ++s) {
                short8 Ah = *(const short8*)&zb[mb + aoff[s]];
                a0 = __builtin_amdgcn_mfma_f32_16x16x32_bf16(Ah, W[0][0][s], a0, 0, 0, 0);
                a1 = __builtin_amdgcn_mfma_f32_16x16x32_bf16(Ah, W[0][1][s], a1, 0, 0, 0);
                a0 = __builtin_amdgcn_mfma_f32_16x16x32_bf16(Ah, W[1][0][s], a0, 0, 0, 0);
                a1 = __builtin_amdgcn_mfma_f32_16x16x32_bf16(Ah, W[1][1][s], a1, 0, 0, 0);
            }
            // sigmoid(x)*softplus(y) in exp2 domain:
            //   a0 = x*log2e, a1 = y*log2e (biases included)
            //   sig = rcp(1 + 2^-a0); sp/ln2 = max(a1,0) + log2(1 + 2^-|a1|)
            #pragma unroll
            for (int r = 0; r < 4; ++r) {
                float sg = frcp(1.f + __builtin_amdgcn_exp2f(-a0[r]));
                float e1 = __builtin_amdgcn_exp2f(-fabsf(a1[r]));
                float u = fmaxf(a1[r], 0.f) + __builtin_amdgcn_logf(1.f + e1);
                macc[mt][r] = __builtin_fmaf(sg, u, macc[mt][r]);
            }
        }
    }

    // fused BN + softplus epilogue; pixel = mt*16 + q*4 + r, cout = c
    const float scale = gamma[c] * (1.f / sqrtf(1.f + 1e-5f));
    const float bet = beta[c];
    #pragma unroll
    for (int mt = 0; mt < 4; ++mt) {
        const size_t ob = nb + (size_t)c * 64 + mt * 16 + q * 4;
        const float4 av = *(const float4*)&atom[ob];
        float av4[4] = {av.x, av.y, av.z, av.w};
        float4 ov;
        float ov4[4];
        #pragma unroll
        for (int r = 0; r < 4; ++r) {
            float aa = av4[r];
            float m = macc[mt][r] * LN2;     // fold exp2-domain factor back, once
            ov4[r] = fsoftplus(aa + (aa + m) * scale + bet);
        }
        ov.x = ov4[0]; ov.y = ov4[1]; ov.z = ov4[2]; ov.w = ov4[3];
        *(float4*)&out[ob] = ov;
    }
}

extern "C" void kernel_launch(void* const* d_in, const int* in_sizes, int n_in,
                              void* d_out, int out_size, void* d_ws, size_t ws_size,
                              hipStream_t stream) {
    const float* atom   = (const float*)d_in[0];
    const int*   esrc   = (const int*)d_in[1];
    const int*   etgt   = (const int*)d_in[2];
    const float* edge_w = (const float*)d_in[3];
    const float* node_w = (const float*)d_in[4];
    const float* lin_w  = (const float*)d_in[5];
    const float* lin_b  = (const float*)d_in[6];
    const float* gamma  = (const float*)d_in[7];
    const float* beta   = (const float*)d_in[8];
    float* out = (float*)d_out;

    const int total = in_sizes[0];      // N*16*8*8
    const int N = total / 1024;         // 8000
    const int E = in_sizes[1];          // 48000

    char* wsb = (char*)d_ws;
    float* zcb       = (float*)wsb;                                   // total fp32
    float* ncb       = (float*)(wsb + (size_t)total * 4);             // total fp32
    short* wfrag_lin = (short*)(wsb + (size_t)total * 8);             // 10240 (16B-aligned)
    short* wfrag_nod = wfrag_lin + 10240;                             // 10240
    int*   counts    = (int*)(wfrag_nod + 10240);                     // N
    int*   cursor    = counts + N;                                    // N
    int*   offsets   = cursor + N;                                    // N+1
    int*   bucket    = offsets + N + 1;                               // E
    int*   nlist     = bucket + E;                                    // N

    const int nhist = (E + 255) / 256;
    const int nconv3 = (N + 3) / 4;     // K3: 256-thread blocks, 4 nodes/block
    const int nscat  = (E + 255) / 256;
    const int nconv4 = (N + 1) / 2;     // K4: 128-thread blocks, 2 nodes/block

    hipMemsetAsync(counts, 0, (size_t)2 * N * 4, stream);             // counts+cursor
    prep_hist_kernel<<<nhist + 1, 256, 0, stream>>>(
        edge_w, node_w, lin_w, esrc, wfrag_lin, wfrag_nod, counts, E, nhist);
    scan_kernel<<<1, 256, 0, stream>>>(counts, offsets, N);
    conv_scatter_order_kernel<<<nconv3 + nscat + 1, 256, 0, stream>>>(
        atom, wfrag_nod, zcb, ncb, esrc, etgt, offsets, cursor, bucket, nlist,
        N, E, nconv3, nscat);
    node_edge_kernel<<<nconv4, 128, 0, stream>>>(
        atom, zcb, ncb, offsets, bucket, nlist, wfrag_lin, lin_b, gamma, beta, out, N);
}